// Round 15
// baseline (101.555 us; speedup 1.0000x reference)
//
#include <hip/hip_runtime.h>

typedef unsigned int u32;
typedef unsigned short u16;
typedef float f32x4 __attribute__((ext_vector_type(4)));
typedef u32 u32x4 __attribute__((ext_vector_type(4)));
typedef u32 u32x2 __attribute__((ext_vector_type(2)));

// ---------- helpers ----------
__device__ __forceinline__ u16 f2bf(float f) {
    u32 u = __builtin_bit_cast(u32, f);
    u = (u + 0x7FFFu + ((u >> 16) & 1u)) >> 16;   // RNE
    return (u16)u;
}

// v_mfma_f32_16x16x32_bf16. A-frag: lane holds A[l&15][8*(l>>4)+j];
// B-frag: B[8*(l>>4)+j][l&15]; C/D: col=l&15, row=(l>>4)*4+reg.
__device__ __forceinline__ void mfma16(f32x4& d, const u32x4& a, const u32x4& b) {
    asm("v_mfma_f32_16x16x32_bf16 %0, %1, %2, %0" : "+v"(d) : "v"(a), "v"(b));
}

// hw exp2 (s_nop covers the TRANS->VALU hazard the compiler can't see in asm)
__device__ __forceinline__ float exp2a(float x) {
    float r;
    asm("v_exp_f32 %0, %1\n\ts_nop 1" : "=v"(r) : "v"(x));
    return r;
}
// pack 2 f32 -> 2 bf16 (RNE), lo in low 16 bits
__device__ __forceinline__ u32 cvtpk(float lo, float hi) {
    u32 r;
    asm("v_cvt_pk_bf16_f32 %0, %1, %2" : "=v"(r) : "v"(lo), "v"(hi));
    return r;
}
// async 16B global -> LDS (m97 pattern: linear LDS dest = base + lane*16)
__device__ __forceinline__ void gload_lds16(const u16* g, u16* l) {
    __builtin_amdgcn_global_load_lds(
        (const __attribute__((address_space(1))) u32*)g,
        (__attribute__((address_space(3))) u32*)l, 16, 0, 0);
}

// ---------- kernels 1 & 3: NT GEMM  C[m][o] = sum_k A[m][k]*B[o][k] ----------
// B is ALWAYS fp32, converted in-staging (r13-proven reg-staged cvt pattern).
// MODE 0: A fp32 (x) fused-cast staging; outputs Q/K scatter + V->VT.
// MODE 1: A bf16 (o) via gload_lds; +bias, fp32 out.
template <int MODE>
__global__ __launch_bounds__(256) void gemm_bt(
    const float* __restrict__ A32, const u16* __restrict__ A16,
    const float* __restrict__ B32, int K, int N,
    u16* __restrict__ qo, u16* __restrict__ ko, u16* __restrict__ vto,
    float* __restrict__ fo, const float* __restrict__ bias)
{
    __shared__ __align__(16) u16 Al[128 * 64];
    __shared__ __align__(16) u16 Bl[128 * 64];
    const int t = threadIdx.x;
    const int w = t >> 6, l = t & 63;
    const int wr = w >> 1, wc = w & 1;
    const int g = l >> 4, li = l & 15;
    const int m0 = blockIdx.x * 128, n0 = blockIdx.y * 128;

    const f32x4 z = {0.f, 0.f, 0.f, 0.f};
    f32x4 acc[4][4];
#pragma unroll
    for (int mi = 0; mi < 4; ++mi)
#pragma unroll
        for (int ni = 0; ni < 4; ++ni) acc[mi][ni] = z;

    // slot geometry (r10-proven): s = rnd*256+t; row p=s>>3, lds chunk cp=s&7,
    // global chunk cg=cp^(p&7). goff in ELEMENTS.
    int goff[4], ldst[4];
#pragma unroll
    for (int rnd = 0; rnd < 4; ++rnd) {
        int s = rnd * 256 + t;
        int p = s >> 3, cp = s & 7;
        int cg = cp ^ (p & 7);
        goff[rnd] = p * K + cg * 8;
        ldst[rnd] = s * 8;
    }

    for (int k0 = 0; k0 < K; k0 += 64) {
        __syncthreads();   // protect previous tile's reads
        if (MODE == 0) {
#pragma unroll
            for (int rnd = 0; rnd < 4; ++rnd) {
                const float* src = A32 + (size_t)m0 * K + k0 + goff[rnd];
                float4 fa = *(const float4*)src;
                float4 fb = *(const float4*)(src + 4);
                u32x4 vv;
                vv.x = cvtpk(fa.x, fa.y);
                vv.y = cvtpk(fa.z, fa.w);
                vv.z = cvtpk(fb.x, fb.y);
                vv.w = cvtpk(fb.z, fb.w);
                *(u32x4*)&Al[ldst[rnd]] = vv;
            }
        } else {
#pragma unroll
            for (int rnd = 0; rnd < 4; ++rnd)
                gload_lds16(A16 + (size_t)m0 * K + k0 + goff[rnd], &Al[ldst[rnd]]);
        }
        // B: fp32 -> bf16 fused staging (weights; L2-resident)
#pragma unroll
        for (int rnd = 0; rnd < 4; ++rnd) {
            const float* src = B32 + (size_t)n0 * K + k0 + goff[rnd];
            float4 fa = *(const float4*)src;
            float4 fb = *(const float4*)(src + 4);
            u32x4 vv;
            vv.x = cvtpk(fa.x, fa.y);
            vv.y = cvtpk(fa.z, fa.w);
            vv.z = cvtpk(fb.x, fb.y);
            vv.w = cvtpk(fb.z, fb.w);
            *(u32x4*)&Bl[ldst[rnd]] = vv;
        }
        __syncthreads();   // drains vmcnt (gload) + lgkmcnt (ds_write)
#pragma unroll
        for (int ks = 0; ks < 2; ++ks) {
            u32x4 af[4], bf[4];
#pragma unroll
            for (int mi = 0; mi < 4; ++mi)
                af[mi] = *(const u32x4*)&Al[(wr * 64 + mi * 16 + li) * 64
                                            + (((ks * 4 + g) ^ (li & 7)) * 8)];
#pragma unroll
            for (int ni = 0; ni < 4; ++ni)
                bf[ni] = *(const u32x4*)&Bl[(wc * 64 + ni * 16 + li) * 64
                                            + (((ks * 4 + g) ^ (li & 7)) * 8)];
#pragma unroll
            for (int mi = 0; mi < 4; ++mi)
#pragma unroll
                for (int ni = 0; ni < 4; ++ni) mfma16(acc[mi][ni], af[mi], bf[ni]);
        }
    }

#pragma unroll
    for (int mi = 0; mi < 4; ++mi) {
#pragma unroll
        for (int ni = 0; ni < 4; ++ni) {
            int o = n0 + wc * 64 + ni * 16 + li;
            int m_base = m0 + wr * 64 + mi * 16 + g * 4;
            if (MODE == 0) {
                int part = o >> 9, oi = o & 511;
                int h = oi >> 6, d = oi & 63;
                int bb = m_base >> 11, nn = m_base & 2047;
                if (part == 2) {
                    u32x2 pv;
                    pv.x = (u32)f2bf(acc[mi][ni][0]) | ((u32)f2bf(acc[mi][ni][1]) << 16);
                    pv.y = (u32)f2bf(acc[mi][ni][2]) | ((u32)f2bf(acc[mi][ni][3]) << 16);
                    *(u32x2*)(vto + ((size_t)(bb * 8 + h) * 64 + d) * 2048 + nn) = pv;
                } else {
                    u16* dst = (part == 0) ? qo : ko;
#pragma unroll
                    for (int r = 0; r < 4; ++r)
                        dst[((size_t)(bb * 8 + h) * 2048 + nn + r) * 64 + d] =
                            f2bf(acc[mi][ni][r]);
                }
            } else {
#pragma unroll
                for (int r = 0; r < 4; ++r)
                    fo[(size_t)(m_base + r) * N + o] = acc[mi][ni][r] + bias[o];
            }
        }
    }
}

// ---------- kernel 2: flash attention (VERBATIM r12/r13, green) ----------
// dbuf gload_lds staging, 1 barrier per double-tile; online softmax with
// defer-max guard (the fmax tree + guard between MFMA and exp STAYS —
// every variant that removed it failed; see journal quarantine).
__global__ __launch_bounds__(256) void attn_kernel(
    const u16* __restrict__ Q, const u16* __restrict__ Kg,
    const u16* __restrict__ VT, u16* __restrict__ O)
{
    __shared__ __align__(16) u16 Kl[2][128 * 64];  // [buf][subtile|p][chunk] swizzled
    __shared__ __align__(16) u16 Vl[2][128 * 64];
    const int t = threadIdx.x;
    const int w = t >> 6, l = t & 63;
    const int g = l >> 4, li = l & 15;
    const int pair = blockIdx.y;
    const int q0 = blockIdx.x * 128 + w * 32;
    const float CEXP = 0.18033688011112042f;    // 0.125 * log2(e)

    u32x4 qf[2][2];
#pragma unroll
    for (int qb = 0; qb < 2; ++qb)
#pragma unroll
        for (int f = 0; f < 2; ++f)
            qf[qb][f] = *(const u32x4*)(Q + ((size_t)pair * 2048 + q0 + qb * 16 + li) * 64
                                          + f * 32 + g * 8);

    const f32x4 z = {0.f, 0.f, 0.f, 0.f};
    f32x4 oacc[2][4];
#pragma unroll
    for (int qb = 0; qb < 2; ++qb)
#pragma unroll
        for (int dc = 0; dc < 4; ++dc) oacc[qb][dc] = z;
    float m_r[2] = {-1e30f, -1e30f};
    float l_r[2] = {0.f, 0.f};

    int koff[4], voff[4], ldo[4];
#pragma unroll
    for (int i = 0; i < 4; ++i) {
        int s = i * 256 + t;
        int sub = s >> 9, sp = s & 511;
        int p = sp >> 3, cp = sp & 7;
        int cg = (cp ^ (p & 7)) * 8;
        int kr = (p & 0x23) | ((p & 0x0C) << 1) | ((p & 0x10) >> 2);
        koff[i] = (sub * 64 + kr) * 64 + cg;
        voff[i] = p * 2048 + sub * 64 + cg;
        ldo[i] = s * 8;
    }
    const u16* kbase = Kg + (size_t)pair * 2048 * 64;
    const u16* vbase = VT + (size_t)pair * 64 * 2048;

#pragma unroll
    for (int i = 0; i < 4; ++i) {
        gload_lds16(kbase + koff[i], &Kl[0][ldo[i]]);
        gload_lds16(vbase + voff[i], &Vl[0][ldo[i]]);
    }
    __syncthreads();

    int cur = 0;
    for (int kt = 0; kt < 16; ++kt) {
        if (kt < 15) {
#pragma unroll
            for (int i = 0; i < 4; ++i) {
                gload_lds16(kbase + (size_t)(kt + 1) * 8192 + koff[i], &Kl[cur ^ 1][ldo[i]]);
                gload_lds16(vbase + (size_t)(kt + 1) * 128 + voff[i], &Vl[cur ^ 1][ldo[i]]);
            }
        }

#pragma unroll
        for (int sub = 0; sub < 2; ++sub) {
            const u16* kl = &Kl[cur][sub * 4096];
            const u16* vl = &Vl[cur][sub * 4096];

            f32x4 st[2][4];
#pragma unroll
            for (int qb = 0; qb < 2; ++qb)
#pragma unroll
                for (int kc = 0; kc < 4; ++kc) st[qb][kc] = z;
#pragma unroll
            for (int kc = 0; kc < 4; ++kc)
#pragma unroll
                for (int f = 0; f < 2; ++f) {
                    u32x4 kf = *(const u32x4*)&kl[(kc * 16 + li) * 64
                                                  + (((4 * f + g) ^ (li & 7)) * 8)];
                    mfma16(st[0][kc], kf, qf[0][f]);
                    mfma16(st[1][kc], kf, qf[1][f]);
                }

            u32x4 pb[2][2];
#pragma unroll
            for (int qb = 0; qb < 2; ++qb) {
                float a0 = fmaxf(fmaxf(st[qb][0][0], st[qb][0][1]), fmaxf(st[qb][0][2], st[qb][0][3]));
                float a1 = fmaxf(fmaxf(st[qb][1][0], st[qb][1][1]), fmaxf(st[qb][1][2], st[qb][1][3]));
                float a2 = fmaxf(fmaxf(st[qb][2][0], st[qb][2][1]), fmaxf(st[qb][2][2], st[qb][2][3]));
                float a3 = fmaxf(fmaxf(st[qb][3][0], st[qb][3][1]), fmaxf(st[qb][3][2], st[qb][3][3]));
                float tmax = fmaxf(fmaxf(a0, a1), fmaxf(a2, a3)) * CEXP;
                if (__any(tmax - m_r[qb] > 8.0f)) {          // rare: tile 0 only
                    float m4 = tmax;
                    m4 = fmaxf(m4, __shfl_xor(m4, 16));
                    m4 = fmaxf(m4, __shfl_xor(m4, 32));
                    float mn = fmaxf(m_r[qb], m4);
                    float alpha = exp2a(m_r[qb] - mn);
                    m_r[qb] = mn;
                    l_r[qb] *= alpha;
#pragma unroll
                    for (int dc = 0; dc < 4; ++dc) oacc[qb][dc] *= alpha;
                }
                float nm = -m_r[qb];
                float ls0 = 0.f, ls1 = 0.f;
#pragma unroll
                for (int kc = 0; kc < 4; ++kc) {
#pragma unroll
                    for (int r = 0; r < 4; ++r) {
                        float pv = exp2a(__builtin_fmaf(st[qb][kc][r], CEXP, nm));
                        st[qb][kc][r] = pv;
                        if (r & 1) ls1 += pv; else ls0 += pv;
                    }
                }
                l_r[qb] += ls0 + ls1;
#pragma unroll
                for (int f = 0; f < 2; ++f) {
                    u32x4 pk;
                    pk.x = cvtpk(st[qb][2 * f][0], st[qb][2 * f][1]);
                    pk.y = cvtpk(st[qb][2 * f][2], st[qb][2 * f][3]);
                    pk.z = cvtpk(st[qb][2 * f + 1][0], st[qb][2 * f + 1][1]);
                    pk.w = cvtpk(st[qb][2 * f + 1][2], st[qb][2 * f + 1][3]);
                    pb[qb][f] = pk;
                }
            }

#pragma unroll
            for (int dc = 0; dc < 4; ++dc)
#pragma unroll
                for (int f = 0; f < 2; ++f) {
                    u32x4 vf = *(const u32x4*)&vl[(dc * 16 + li) * 64
                                                  + (((4 * f + g) ^ (li & 7)) * 8)];
                    mfma16(oacc[0][dc], vf, pb[0][f]);
                    mfma16(oacc[1][dc], vf, pb[1][f]);
                }
        }

        __syncthreads();
        cur ^= 1;
    }

    const int bb = pair >> 3, h = pair & 7;
#pragma unroll
    for (int qb = 0; qb < 2; ++qb) {
        float ls = l_r[qb];
        ls += __shfl_xor(ls, 16);
        ls += __shfl_xor(ls, 32);
        float inv = 1.f / ls;
        u16* orow = O + ((size_t)bb * 2048 + q0 + qb * 16 + li) * 512 + h * 64;
#pragma unroll
        for (int dc = 0; dc < 4; ++dc) {
            u32x2 pv;
            pv.x = cvtpk(oacc[qb][dc][0] * inv, oacc[qb][dc][1] * inv);
            pv.y = cvtpk(oacc[qb][dc][2] * inv, oacc[qb][dc][3] * inv);
            *(u32x2*)(orow + dc * 16 + 4 * g) = pv;
        }
    }
}

// ---------- launcher (3 dispatches: gemm0, attn, gemm1) ----------
extern "C" void kernel_launch(void* const* d_in, const int* in_sizes, int n_in,
                              void* d_out, int out_size, void* d_ws, size_t ws_size,
                              hipStream_t stream) {
    const float* x     = (const float*)d_in[0];   // [4,2048,512]
    const float* w_qkv = (const float*)d_in[1];   // [1536,512]
    const float* w_out = (const float*)d_in[2];   // [512,512]
    const float* b_out = (const float*)d_in[3];   // [512]
    float* out = (float*)d_out;                   // [4,2048,512] fp32

    char* ws = (char*)d_ws;
    u16* o  = (u16*)(ws + 0);           // O [8192][512]
    u16* q  = (u16*)(ws + 10485760);    // 8 MiB   Q  [32][2048][64]
    u16* kk = (u16*)(ws + 18874368);    // 8 MiB   K  [32][2048][64]
    u16* vt = (u16*)(ws + 27262976);    // 8 MiB   VT [32][64][2048]

    // qkv = x @ w_qkv.T  (M=8192, N=1536, K=512); x and w_qkv cast in-staging
    gemm_bt<0><<<dim3(64, 12), 256, 0, stream>>>(x, nullptr, w_qkv, 512, 1536,
                                                 q, kk, vt, nullptr, nullptr);
    attn_kernel<<<dim3(16, 32), 256, 0, stream>>>(q, kk, vt, o);

    // out = O @ w_out.T + b_out  (M=8192, N=512, K=512); w_out cast in-staging
    gemm_bt<1><<<dim3(64, 4), 256, 0, stream>>>(nullptr, o, w_out, 512, 512,
                                                nullptr, nullptr, nullptr, out, b_out);
}

// Round 17
// 98.058 us; speedup vs baseline: 1.0357x; 1.0357x over previous
//
#include <hip/hip_runtime.h>

typedef unsigned int u32;
typedef unsigned short u16;
typedef float f32x4 __attribute__((ext_vector_type(4)));
typedef u32 u32x4 __attribute__((ext_vector_type(4)));
typedef u32 u32x2 __attribute__((ext_vector_type(2)));

// ---------- helpers ----------
__device__ __forceinline__ u16 f2bf(float f) {
    u32 u = __builtin_bit_cast(u32, f);
    u = (u + 0x7FFFu + ((u >> 16) & 1u)) >> 16;   // RNE
    return (u16)u;
}

// v_mfma_f32_16x16x32_bf16. A-frag: lane holds A[l&15][8*(l>>4)+j];
// B-frag: B[8*(l>>4)+j][l&15]; C/D: col=l&15, row=(l>>4)*4+reg.
__device__ __forceinline__ void mfma16(f32x4& d, const u32x4& a, const u32x4& b) {
    asm("v_mfma_f32_16x16x32_bf16 %0, %1, %2, %0" : "+v"(d) : "v"(a), "v"(b));
}

// hw exp2 (s_nop covers the TRANS->VALU hazard the compiler can't see in asm)
__device__ __forceinline__ float exp2a(float x) {
    float r;
    asm("v_exp_f32 %0, %1\n\ts_nop 1" : "=v"(r) : "v"(x));
    return r;
}
// pack 2 f32 -> 2 bf16 (RNE), lo in low 16 bits
__device__ __forceinline__ u32 cvtpk(float lo, float hi) {
    u32 r;
    asm("v_cvt_pk_bf16_f32 %0, %1, %2" : "=v"(r) : "v"(lo), "v"(hi));
    return r;
}
// async 16B global -> LDS (m97 pattern: linear LDS dest = base + lane*16)
__device__ __forceinline__ void gload_lds16(const u16* g, u16* l) {
    __builtin_amdgcn_global_load_lds(
        (const __attribute__((address_space(1))) u32*)g,
        (__attribute__((address_space(3))) u32*)l, 16, 0, 0);
}

// ---------- kernel 1: fp32 -> bf16 cast, WEIGHTS ONLY (r13-proven) ----------
__global__ __launch_bounds__(256) void cast2_kernel(
    const float* __restrict__ wq, const float* __restrict__ wo,
    u16* __restrict__ wqb, u16* __restrict__ wob) {
    int bid = blockIdx.x;
    const float* src;
    u16* dst;
    int base;
    if (bid < 384) { src = wq; dst = wqb; base = bid * 2048; }
    else           { src = wo; dst = wob; base = (bid - 384) * 2048; }
    int i = base + threadIdx.x * 8;
    float4 a = *(const float4*)(src + i);
    float4 b = *(const float4*)(src + i + 4);
    u32x4 r;
    r.x = (u32)f2bf(a.x) | ((u32)f2bf(a.y) << 16);
    r.y = (u32)f2bf(a.z) | ((u32)f2bf(a.w) << 16);
    r.z = (u32)f2bf(b.x) | ((u32)f2bf(b.y) << 16);
    r.w = (u32)f2bf(b.z) | ((u32)f2bf(b.w) << 16);
    *(u32x4*)(dst + i) = r;
}

// ---------- kernel 2: QKV GEMM (VERBATIM r13, best measured) ----------
// A fp32 (x) fused-cast staging; B bf16 gload; Q/K scatter + V->VT.
__global__ __launch_bounds__(256) void gemm_qkv(
    const float* __restrict__ A32, const u16* __restrict__ B, int K,
    u16* __restrict__ qo, u16* __restrict__ ko, u16* __restrict__ vto)
{
    __shared__ __align__(16) u16 Al[128 * 64];
    __shared__ __align__(16) u16 Bl[128 * 64];
    const int t = threadIdx.x;
    const int w = t >> 6, l = t & 63;
    const int wr = w >> 1, wc = w & 1;
    const int g = l >> 4, li = l & 15;
    const int m0 = blockIdx.x * 128, n0 = blockIdx.y * 128;

    const f32x4 z = {0.f, 0.f, 0.f, 0.f};
    f32x4 acc[4][4];
#pragma unroll
    for (int mi = 0; mi < 4; ++mi)
#pragma unroll
        for (int ni = 0; ni < 4; ++ni) acc[mi][ni] = z;

    int goff[4], ldst[4];
#pragma unroll
    for (int rnd = 0; rnd < 4; ++rnd) {
        int s = rnd * 256 + t;
        int p = s >> 3, cp = s & 7;
        int cg = cp ^ (p & 7);
        goff[rnd] = p * K + cg * 8;
        ldst[rnd] = s * 8;
    }

    for (int k0 = 0; k0 < K; k0 += 64) {
        __syncthreads();   // protect previous tile's reads
#pragma unroll
        for (int rnd = 0; rnd < 4; ++rnd) {
            const float* src = A32 + (size_t)m0 * K + k0 + goff[rnd];
            float4 fa = *(const float4*)src;
            float4 fb = *(const float4*)(src + 4);
            u32x4 vv;
            vv.x = cvtpk(fa.x, fa.y);
            vv.y = cvtpk(fa.z, fa.w);
            vv.z = cvtpk(fb.x, fb.y);
            vv.w = cvtpk(fb.z, fb.w);
            *(u32x4*)&Al[ldst[rnd]] = vv;
        }
#pragma unroll
        for (int rnd = 0; rnd < 4; ++rnd)
            gload_lds16(B + (size_t)n0 * K + k0 + goff[rnd], &Bl[ldst[rnd]]);
        __syncthreads();   // drains vmcnt (gload) + lgkmcnt (ds_write)
#pragma unroll
        for (int ks = 0; ks < 2; ++ks) {
            u32x4 af[4], bf[4];
#pragma unroll
            for (int mi = 0; mi < 4; ++mi)
                af[mi] = *(const u32x4*)&Al[(wr * 64 + mi * 16 + li) * 64
                                            + (((ks * 4 + g) ^ (li & 7)) * 8)];
#pragma unroll
            for (int ni = 0; ni < 4; ++ni)
                bf[ni] = *(const u32x4*)&Bl[(wc * 64 + ni * 16 + li) * 64
                                            + (((ks * 4 + g) ^ (li & 7)) * 8)];
#pragma unroll
            for (int mi = 0; mi < 4; ++mi)
#pragma unroll
                for (int ni = 0; ni < 4; ++ni) mfma16(acc[mi][ni], af[mi], bf[ni]);
        }
    }

#pragma unroll
    for (int mi = 0; mi < 4; ++mi) {
#pragma unroll
        for (int ni = 0; ni < 4; ++ni) {
            int o = n0 + wc * 64 + ni * 16 + li;
            int m_base = m0 + wr * 64 + mi * 16 + g * 4;
            int part = o >> 9, oi = o & 511;
            int h = oi >> 6, d = oi & 63;
            int bb = m_base >> 11, nn = m_base & 2047;
            if (part == 2) {
                u32x2 pv;
                pv.x = (u32)f2bf(acc[mi][ni][0]) | ((u32)f2bf(acc[mi][ni][1]) << 16);
                pv.y = (u32)f2bf(acc[mi][ni][2]) | ((u32)f2bf(acc[mi][ni][3]) << 16);
                *(u32x2*)(vto + ((size_t)(bb * 8 + h) * 64 + d) * 2048 + nn) = pv;
            } else {
                u16* dst = (part == 0) ? qo : ko;
#pragma unroll
                for (int r = 0; r < 4; ++r)
                    dst[((size_t)(bb * 8 + h) * 2048 + nn + r) * 64 + d] =
                        f2bf(acc[mi][ni][r]);
            }
        }
    }
}

// ---------- kernel 4: out GEMM, BN=64 (parameter-level change on r10 template) ----------
// 128x64 tile, grid (64,8) = 512 blocks = 2 blocks/CU (was 1 at BN=128).
// Wave tile 64x32, acc[4][2]; B-tile 64 rows staged in 2 slots. Same swizzle
// algebra (all row offsets multiples of 8 -> row&7 == li&7 holds).
__global__ __launch_bounds__(256) void gemm_out(
    const u16* __restrict__ A16, const u16* __restrict__ B,
    float* __restrict__ fo, const float* __restrict__ bias)
{
    const int K = 512, N = 512;
    __shared__ __align__(16) u16 Al[128 * 64];
    __shared__ __align__(16) u16 Bl[64 * 64];
    const int t = threadIdx.x;
    const int w = t >> 6, l = t & 63;
    const int wr = w >> 1, wc = w & 1;
    const int g = l >> 4, li = l & 15;
    const int m0 = blockIdx.x * 128, n0 = blockIdx.y * 64;

    const f32x4 z = {0.f, 0.f, 0.f, 0.f};
    f32x4 acc[4][2];
#pragma unroll
    for (int mi = 0; mi < 4; ++mi)
#pragma unroll
        for (int ni = 0; ni < 2; ++ni) acc[mi][ni] = z;

    int goffA[4], ldstA[4], goffB[2], ldstB[2];
#pragma unroll
    for (int rnd = 0; rnd < 4; ++rnd) {
        int s = rnd * 256 + t;
        int p = s >> 3, cp = s & 7;
        int cg = cp ^ (p & 7);
        goffA[rnd] = p * K + cg * 8;
        ldstA[rnd] = s * 8;
    }
#pragma unroll
    for (int rnd = 0; rnd < 2; ++rnd) {
        int s = rnd * 256 + t;
        int p = s >> 3, cp = s & 7;
        int cg = cp ^ (p & 7);
        goffB[rnd] = p * K + cg * 8;
        ldstB[rnd] = s * 8;
    }

    for (int k0 = 0; k0 < K; k0 += 64) {
        __syncthreads();
#pragma unroll
        for (int rnd = 0; rnd < 4; ++rnd)
            gload_lds16(A16 + (size_t)m0 * K + k0 + goffA[rnd], &Al[ldstA[rnd]]);
#pragma unroll
        for (int rnd = 0; rnd < 2; ++rnd)
            gload_lds16(B + (size_t)n0 * K + k0 + goffB[rnd], &Bl[ldstB[rnd]]);
        __syncthreads();
#pragma unroll
        for (int ks = 0; ks < 2; ++ks) {
            u32x4 af[4], bf[2];
#pragma unroll
            for (int mi = 0; mi < 4; ++mi)
                af[mi] = *(const u32x4*)&Al[(wr * 64 + mi * 16 + li) * 64
                                            + (((ks * 4 + g) ^ (li & 7)) * 8)];
#pragma unroll
            for (int ni = 0; ni < 2; ++ni)
                bf[ni] = *(const u32x4*)&Bl[(wc * 32 + ni * 16 + li) * 64
                                            + (((ks * 4 + g) ^ (li & 7)) * 8)];
#pragma unroll
            for (int mi = 0; mi < 4; ++mi)
#pragma unroll
                for (int ni = 0; ni < 2; ++ni) mfma16(acc[mi][ni], af[mi], bf[ni]);
        }
    }

#pragma unroll
    for (int mi = 0; mi < 4; ++mi) {
#pragma unroll
        for (int ni = 0; ni < 2; ++ni) {
            int o = n0 + wc * 32 + ni * 16 + li;
            int m_base = m0 + wr * 64 + mi * 16 + g * 4;
#pragma unroll
            for (int r = 0; r < 4; ++r)
                fo[(size_t)(m_base + r) * N + o] = acc[mi][ni][r] + bias[o];
        }
    }
}

// ---------- kernel 3: flash attention (VERBATIM r12/r13, green) ----------
// dbuf gload_lds staging (4-wave blocks only — 2-wave prefetch quarantined),
// online softmax with defer-max guard (guard STAYS — see journal quarantine).
__global__ __launch_bounds__(256) void attn_kernel(
    const u16* __restrict__ Q, const u16* __restrict__ Kg,
    const u16* __restrict__ VT, u16* __restrict__ O)
{
    __shared__ __align__(16) u16 Kl[2][128 * 64];  // [buf][subtile|p][chunk] swizzled
    __shared__ __align__(16) u16 Vl[2][128 * 64];
    const int t = threadIdx.x;
    const int w = t >> 6, l = t & 63;
    const int g = l >> 4, li = l & 15;
    const int pair = blockIdx.y;
    const int q0 = blockIdx.x * 128 + w * 32;
    const float CEXP = 0.18033688011112042f;    // 0.125 * log2(e)

    u32x4 qf[2][2];
#pragma unroll
    for (int qb = 0; qb < 2; ++qb)
#pragma unroll
        for (int f = 0; f < 2; ++f)
            qf[qb][f] = *(const u32x4*)(Q + ((size_t)pair * 2048 + q0 + qb * 16 + li) * 64
                                          + f * 32 + g * 8);

    const f32x4 z = {0.f, 0.f, 0.f, 0.f};
    f32x4 oacc[2][4];
#pragma unroll
    for (int qb = 0; qb < 2; ++qb)
#pragma unroll
        for (int dc = 0; dc < 4; ++dc) oacc[qb][dc] = z;
    float m_r[2] = {-1e30f, -1e30f};
    float l_r[2] = {0.f, 0.f};

    int koff[4], voff[4], ldo[4];
#pragma unroll
    for (int i = 0; i < 4; ++i) {
        int s = i * 256 + t;
        int sub = s >> 9, sp = s & 511;
        int p = sp >> 3, cp = sp & 7;
        int cg = (cp ^ (p & 7)) * 8;
        int kr = (p & 0x23) | ((p & 0x0C) << 1) | ((p & 0x10) >> 2);
        koff[i] = (sub * 64 + kr) * 64 + cg;
        voff[i] = p * 2048 + sub * 64 + cg;
        ldo[i] = s * 8;
    }
    const u16* kbase = Kg + (size_t)pair * 2048 * 64;
    const u16* vbase = VT + (size_t)pair * 64 * 2048;

#pragma unroll
    for (int i = 0; i < 4; ++i) {
        gload_lds16(kbase + koff[i], &Kl[0][ldo[i]]);
        gload_lds16(vbase + voff[i], &Vl[0][ldo[i]]);
    }
    __syncthreads();

    int cur = 0;
    for (int kt = 0; kt < 16; ++kt) {
        if (kt < 15) {
#pragma unroll
            for (int i = 0; i < 4; ++i) {
                gload_lds16(kbase + (size_t)(kt + 1) * 8192 + koff[i], &Kl[cur ^ 1][ldo[i]]);
                gload_lds16(vbase + (size_t)(kt + 1) * 128 + voff[i], &Vl[cur ^ 1][ldo[i]]);
            }
        }

#pragma unroll
        for (int sub = 0; sub < 2; ++sub) {
            const u16* kl = &Kl[cur][sub * 4096];
            const u16* vl = &Vl[cur][sub * 4096];

            f32x4 st[2][4];
#pragma unroll
            for (int qb = 0; qb < 2; ++qb)
#pragma unroll
                for (int kc = 0; kc < 4; ++kc) st[qb][kc] = z;
#pragma unroll
            for (int kc = 0; kc < 4; ++kc)
#pragma unroll
                for (int f = 0; f < 2; ++f) {
                    u32x4 kf = *(const u32x4*)&kl[(kc * 16 + li) * 64
                                                  + (((4 * f + g) ^ (li & 7)) * 8)];
                    mfma16(st[0][kc], kf, qf[0][f]);
                    mfma16(st[1][kc], kf, qf[1][f]);
                }

            u32x4 pb[2][2];
#pragma unroll
            for (int qb = 0; qb < 2; ++qb) {
                float a0 = fmaxf(fmaxf(st[qb][0][0], st[qb][0][1]), fmaxf(st[qb][0][2], st[qb][0][3]));
                float a1 = fmaxf(fmaxf(st[qb][1][0], st[qb][1][1]), fmaxf(st[qb][1][2], st[qb][1][3]));
                float a2 = fmaxf(fmaxf(st[qb][2][0], st[qb][2][1]), fmaxf(st[qb][2][2], st[qb][2][3]));
                float a3 = fmaxf(fmaxf(st[qb][3][0], st[qb][3][1]), fmaxf(st[qb][3][2], st[qb][3][3]));
                float tmax = fmaxf(fmaxf(a0, a1), fmaxf(a2, a3)) * CEXP;
                if (__any(tmax - m_r[qb] > 8.0f)) {          // rare: tile 0 only
                    float m4 = tmax;
                    m4 = fmaxf(m4, __shfl_xor(m4, 16));
                    m4 = fmaxf(m4, __shfl_xor(m4, 32));
                    float mn = fmaxf(m_r[qb], m4);
                    float alpha = exp2a(m_r[qb] - mn);
                    m_r[qb] = mn;
                    l_r[qb] *= alpha;
#pragma unroll
                    for (int dc = 0; dc < 4; ++dc) oacc[qb][dc] *= alpha;
                }
                float nm = -m_r[qb];
                float ls0 = 0.f, ls1 = 0.f;
#pragma unroll
                for (int kc = 0; kc < 4; ++kc) {
#pragma unroll
                    for (int r = 0; r < 4; ++r) {
                        float pv = exp2a(__builtin_fmaf(st[qb][kc][r], CEXP, nm));
                        st[qb][kc][r] = pv;
                        if (r & 1) ls1 += pv; else ls0 += pv;
                    }
                }
                l_r[qb] += ls0 + ls1;
#pragma unroll
                for (int f = 0; f < 2; ++f) {
                    u32x4 pk;
                    pk.x = cvtpk(st[qb][2 * f][0], st[qb][2 * f][1]);
                    pk.y = cvtpk(st[qb][2 * f][2], st[qb][2 * f][3]);
                    pk.z = cvtpk(st[qb][2 * f + 1][0], st[qb][2 * f + 1][1]);
                    pk.w = cvtpk(st[qb][2 * f + 1][2], st[qb][2 * f + 1][3]);
                    pb[qb][f] = pk;
                }
            }

#pragma unroll
            for (int dc = 0; dc < 4; ++dc)
#pragma unroll
                for (int f = 0; f < 2; ++f) {
                    u32x4 vf = *(const u32x4*)&vl[(dc * 16 + li) * 64
                                                  + (((4 * f + g) ^ (li & 7)) * 8)];
                    mfma16(oacc[0][dc], vf, pb[0][f]);
                    mfma16(oacc[1][dc], vf, pb[1][f]);
                }
        }

        __syncthreads();
        cur ^= 1;
    }

    const int bb = pair >> 3, h = pair & 7;
#pragma unroll
    for (int qb = 0; qb < 2; ++qb) {
        float ls = l_r[qb];
        ls += __shfl_xor(ls, 16);
        ls += __shfl_xor(ls, 32);
        float inv = 1.f / ls;
        u16* orow = O + ((size_t)bb * 2048 + q0 + qb * 16 + li) * 512 + h * 64;
#pragma unroll
        for (int dc = 0; dc < 4; ++dc) {
            u32x2 pv;
            pv.x = cvtpk(oacc[qb][dc][0] * inv, oacc[qb][dc][1] * inv);
            pv.y = cvtpk(oacc[qb][dc][2] * inv, oacc[qb][dc][3] * inv);
            *(u32x2*)(orow + dc * 16 + 4 * g) = pv;
        }
    }
}

// ---------- launcher ----------
extern "C" void kernel_launch(void* const* d_in, const int* in_sizes, int n_in,
                              void* d_out, int out_size, void* d_ws, size_t ws_size,
                              hipStream_t stream) {
    const float* x     = (const float*)d_in[0];   // [4,2048,512]
    const float* w_qkv = (const float*)d_in[1];   // [1536,512]
    const float* w_out = (const float*)d_in[2];   // [512,512]
    const float* b_out = (const float*)d_in[3];   // [512]
    float* out = (float*)d_out;                   // [4,2048,512] fp32

    char* ws = (char*)d_ws;
    u16* o  = (u16*)(ws + 0);           // O [8192][512]
    u16* wq = (u16*)(ws + 8388608);     // 1.5 MiB
    u16* wo = (u16*)(ws + 9961472);     // 0.5 MiB
    u16* q  = (u16*)(ws + 10485760);    // 8 MiB   Q  [32][2048][64]
    u16* kk = (u16*)(ws + 18874368);    // 8 MiB   K  [32][2048][64]
    u16* vt = (u16*)(ws + 27262976);    // 8 MiB   VT [32][64][2048]

    cast2_kernel<<<512, 256, 0, stream>>>(w_qkv, w_out, wq, wo);

    // qkv = x @ w_qkv.T  (M=8192, N=1536, K=512); x cast fused into A-staging
    gemm_qkv<<<dim3(64, 12), 256, 0, stream>>>(x, wq, 512, q, kk, vt);
    attn_kernel<<<dim3(16, 32), 256, 0, stream>>>(q, kk, vt, o);

    // out = O @ w_out.T + b_out  (M=8192, N=512, K=512); BN=64 -> 512 blocks
    gemm_out<<<dim3(64, 8), 256, 0, stream>>>(o, wo, out, b_out);
}